// Round 4
// baseline (82.870 us; speedup 1.0000x reference)
//
#include <hip/hip_runtime.h>
#include <math.h>

#define BATCH 32
#define CH    256
#define HH    64
#define WW    64
#define HW    (HH * WW)                  // 4096
#define NPIX  (BATCH * HW)               // 131072
#define PG    (NPIX / 4)                 // 32768 float4 pixel-groups
#define NTOT  ((size_t)BATCH * CH * HW)  // 33554432
#define NCHUNK 4
#define CCHUNK (CH / NCHUNK)             // 64

typedef float floatx4 __attribute__((ext_vector_type(4)));

// Kernel 1: partial channel sum+max over a 64-channel chunk, float4 pixels.
// 512 blocks x 256 threads; each thread streams 64 channels (independent loads).
__global__ __launch_bounds__(256) void sa_pool_partial(
    const float* __restrict__ x,
    float4* __restrict__ pSum, float4* __restrict__ pMax) {
    int t = blockIdx.x * 256 + threadIdx.x;             // [0, PG*NCHUNK)
    int pg    = t & (PG - 1);
    int chunk = t >> 15;
    int b   = pg >> 10;                                 // 1024 groups per image
    int hwg = pg & 1023;
    const float4* p = reinterpret_cast<const float4*>(
        x + (size_t)b * CH * HW + (size_t)chunk * CCHUNK * HW) + hwg;
    float4 s = make_float4(0.f, 0.f, 0.f, 0.f);
    float4 m = make_float4(-INFINITY, -INFINITY, -INFINITY, -INFINITY);
#pragma unroll 8
    for (int c = 0; c < CCHUNK; ++c) {
        float4 v = p[c * (HW / 4)];
        s.x += v.x; s.y += v.y; s.z += v.z; s.w += v.w;
        m.x = fmaxf(m.x, v.x); m.y = fmaxf(m.y, v.y);
        m.z = fmaxf(m.z, v.z); m.w = fmaxf(m.w, v.w);
    }
    pSum[chunk * PG + pg] = s;
    pMax[chunk * PG + pg] = m;
}

// Kernel 2: combine partials (with 3-row halo) + 7x7 conv + bias + sigmoid.
// Block = (image b, 16-row strip s). 128 blocks x 256 threads.
__global__ __launch_bounds__(256) void sa_comb_conv(
    const float4* __restrict__ pSum, const float4* __restrict__ pMax,
    const float* __restrict__ wgt, const float* __restrict__ bias,
    float* __restrict__ attn) {
    __shared__ float pooled[22][64];   // up to 16+6 halo rows
    __shared__ float wq[49];
    int bidx = blockIdx.x;
    int b = bidx >> 2;
    int s = bidx & 3;
    int t = threadIdx.x;
    if (t < 49) wq[t] = wgt[t];
    int rowbase = 16 * s - 3; if (rowbase < 0) rowbase = 0;
    int rowend  = 16 * s + 19; if (rowend > 64) rowend = 64;
    int nrows   = rowend - rowbase;
    int ngroups = nrows * 16;                 // float4 groups to combine
    const float inv = 1.0f / (float)CH;
    for (int i = t; i < ngroups; i += 256) {
        int lr = i >> 4, cg = i & 15;
        int pg = b * 1024 + (rowbase + lr) * 16 + cg;
        float4 sv = make_float4(0.f, 0.f, 0.f, 0.f);
        float4 mv = make_float4(-INFINITY, -INFINITY, -INFINITY, -INFINITY);
#pragma unroll
        for (int c = 0; c < NCHUNK; ++c) {
            float4 a  = pSum[c * PG + pg];
            float4 bm = pMax[c * PG + pg];
            sv.x += a.x; sv.y += a.y; sv.z += a.z; sv.w += a.w;
            mv.x = fmaxf(mv.x, bm.x); mv.y = fmaxf(mv.y, bm.y);
            mv.z = fmaxf(mv.z, bm.z); mv.w = fmaxf(mv.w, bm.w);
        }
        pooled[lr][cg * 4 + 0] = sv.x * inv + mv.x;
        pooled[lr][cg * 4 + 1] = sv.y * inv + mv.y;
        pooled[lr][cg * 4 + 2] = sv.z * inv + mv.z;
        pooled[lr][cg * 4 + 3] = sv.w * inv + mv.w;
    }
    __syncthreads();
    float bv = bias[0];
    for (int i = t; i < 1024; i += 256) {
        int r = i >> 6, w = i & 63;
        int gr = 16 * s + r;
        float acc = bv;
#pragma unroll
        for (int kh = 0; kh < 7; ++kh) {
            int gr2 = gr + kh - 3;
            if (gr2 < 0 || gr2 >= HH) continue;
            int lr = gr2 - rowbase;
#pragma unroll
            for (int kw = 0; kw < 7; ++kw) {
                int w2 = w + kw - 3;
                if (w2 < 0 || w2 >= WW) continue;
                acc += pooled[lr][w2] * wq[kh * 7 + kw];
            }
        }
        attn[b * HW + gr * 64 + w] = 1.0f / (1.0f + __expf(-acc));
    }
}

// Kernel 3: out = x * attn. Each thread owns one (image, pixel-group) and a
// 64-channel quarter: attn4 loaded ONCE into registers, reused 64x.
// 512 blocks x 256 threads.
__global__ __launch_bounds__(256) void sa_mul(
    const float* __restrict__ x, const float4* __restrict__ attn4,
    float* __restrict__ out) {
    int t = blockIdx.x * 256 + threadIdx.x;   // [0, 131072)
    int pg = t & (PG - 1);
    int cq = t >> 15;                         // channel quarter
    int b  = pg >> 10;
    float4 a = attn4[pg];                     // pg == b*1024 + hwg
    size_t base = (size_t)b * CH * HW + (size_t)cq * CCHUNK * HW
                + (size_t)(pg & 1023) * 4;
    const float* xp = x + base;
    float* op = out + base;
#pragma unroll 8
    for (int c = 0; c < CCHUNK; ++c) {
        float4 v = *reinterpret_cast<const float4*>(xp + (size_t)c * HW);
        floatx4 o;
        o.x = v.x * a.x; o.y = v.y * a.y; o.z = v.z * a.z; o.w = v.w * a.w;
        __builtin_nontemporal_store(o, reinterpret_cast<floatx4*>(op + (size_t)c * HW));
    }
}

extern "C" void kernel_launch(void* const* d_in, const int* in_sizes, int n_in,
                              void* d_out, int out_size, void* d_ws, size_t ws_size,
                              hipStream_t stream) {
    const float* x    = (const float*)d_in[0];
    const float* wgt  = (const float*)d_in[1];
    const float* bias = (const float*)d_in[2];
    float* out = (float*)d_out;

    // ws layout (floats): attn [NPIX], pSum [NCHUNK*PG*4], pMax [NCHUNK*PG*4]
    float*  attn = (float*)d_ws;
    float4* pSum = reinterpret_cast<float4*>(attn + NPIX);
    float4* pMax = pSum + (size_t)NCHUNK * PG;

    sa_pool_partial<<<dim3((PG * NCHUNK) / 256), dim3(256), 0, stream>>>(
        x, pSum, pMax);                        // 512 blocks
    sa_comb_conv<<<dim3(BATCH * 4), dim3(256), 0, stream>>>(
        pSum, pMax, wgt, bias, attn);          // 128 blocks
    sa_mul<<<dim3((PG * NCHUNK) / 256), dim3(256), 0, stream>>>(
        x, reinterpret_cast<const float4*>(attn), out);   // 512 blocks
}

// Round 5
// 80.383 us; speedup vs baseline: 1.0309x; 1.0309x over previous
//
#include <hip/hip_runtime.h>
#include <math.h>

#define BATCH 32
#define CH    256
#define HH    64
#define WW    64
#define HW    (HH * WW)                  // 4096
#define NPIX  (BATCH * HW)               // 131072
#define NTOT  ((size_t)BATCH * CH * HW)  // 33554432

// Per-block geometry: 128 contiguous pixels (2 rows) x all 256 channels.
// 32 float4 pixel-groups per block; 8 channel-chunks of 32.
#define PIX_PER_BLK 128
#define GRP_PER_BLK 32                   // float4 groups
#define NCHUNK 8
#define CCHUNK 32
#define NBLK  (NPIX / PIX_PER_BLK)       // 1024

typedef float floatx4 __attribute__((ext_vector_type(4)));

// K1: channel-wise mean+max -> pooled [B*H*W], via in-block LDS combine.
// grid 1024 x 256. Thread (g = t&31, c = t>>5): 32-channel partial over
// float4 pixel-group g.
__global__ __launch_bounds__(256) void sa_pool(
    const float* __restrict__ x, float4* __restrict__ pooled4) {
    __shared__ float4 sS[NCHUNK][GRP_PER_BLK];
    __shared__ float4 sM[NCHUNK][GRP_PER_BLK];
    int t = threadIdx.x;
    int g = t & 31;
    int c = t >> 5;
    int img = blockIdx.x >> 5;           // 32 blocks per image
    int seg = blockIdx.x & 31;
    int pix0 = seg * PIX_PER_BLK;
    const float* p = x + (size_t)img * CH * HW + (size_t)c * CCHUNK * HW
                   + pix0 + g * 4;
    float4 s = make_float4(0.f, 0.f, 0.f, 0.f);
    float4 m = make_float4(-INFINITY, -INFINITY, -INFINITY, -INFINITY);
#pragma unroll 8
    for (int i = 0; i < CCHUNK; ++i) {
        float4 v = *reinterpret_cast<const float4*>(p + (size_t)i * HW);
        s.x += v.x; s.y += v.y; s.z += v.z; s.w += v.w;
        m.x = fmaxf(m.x, v.x); m.y = fmaxf(m.y, v.y);
        m.z = fmaxf(m.z, v.z); m.w = fmaxf(m.w, v.w);
    }
    sS[c][g] = s;
    sM[c][g] = m;
    __syncthreads();
    if (t < GRP_PER_BLK) {
        float4 as = sS[0][t];
        float4 am = sM[0][t];
#pragma unroll
        for (int cc = 1; cc < NCHUNK; ++cc) {
            float4 bs = sS[cc][t];
            float4 bm = sM[cc][t];
            as.x += bs.x; as.y += bs.y; as.z += bs.z; as.w += bs.w;
            am.x = fmaxf(am.x, bm.x); am.y = fmaxf(am.y, bm.y);
            am.z = fmaxf(am.z, bm.z); am.w = fmaxf(am.w, bm.w);
        }
        const float inv = 1.0f / (float)CH;
        float4 o;
        o.x = as.x * inv + am.x; o.y = as.y * inv + am.y;
        o.z = as.z * inv + am.z; o.w = as.w * inv + am.w;
        pooled4[(img * HW + pix0) / 4 + t] = o;
    }
}

// K2: conv(7x7)+sigmoid in LDS, then out = x * attn streamed over channels.
// grid 1024 x 256, same strip mapping as K1.
__global__ __launch_bounds__(256) void sa_conv_mul(
    const float* __restrict__ x, const float4* __restrict__ pooled4,
    const float* __restrict__ wgt, const float* __restrict__ bias,
    float* __restrict__ out) {
    __shared__ float pool_s[8][64];      // halo rows (<=8)
    __shared__ float attn_s[PIX_PER_BLK];
    __shared__ float wq[49];
    int t = threadIdx.x;
    int img = blockIdx.x >> 5;
    int seg = blockIdx.x & 31;
    int pix0 = seg * PIX_PER_BLK;
    int r0 = seg * 2;                    // first of 2 rows
    if (t < 49) wq[t] = wgt[t];
    int lo = r0 - 3; if (lo < 0) lo = 0;
    int hi = r0 + 4; if (hi > 63) hi = 63;
    int nrows = hi - lo + 1;             // <= 8
    // load halo pooled rows: nrows*16 float4 groups
    if (t < nrows * 16) {
        int lr = t >> 4, cg = t & 15;
        float4 v = pooled4[img * (HW / 4) + (lo + lr) * 16 + cg];
        pool_s[lr][cg * 4 + 0] = v.x;
        pool_s[lr][cg * 4 + 1] = v.y;
        pool_s[lr][cg * 4 + 2] = v.z;
        pool_s[lr][cg * 4 + 3] = v.w;
    }
    __syncthreads();
    if (t < PIX_PER_BLK) {
        int r = r0 + (t >> 6);
        int w = t & 63;
        float acc = bias[0];
#pragma unroll
        for (int kh = 0; kh < 7; ++kh) {
            int gr2 = r + kh - 3;
            if (gr2 < 0 || gr2 >= HH) continue;
            int lr = gr2 - lo;
#pragma unroll
            for (int kw = 0; kw < 7; ++kw) {
                int w2 = w + kw - 3;
                if (w2 < 0 || w2 >= WW) continue;
                acc += pool_s[lr][w2] * wq[kh * 7 + kw];
            }
        }
        attn_s[t] = 1.0f / (1.0f + __expf(-acc));
    }
    __syncthreads();
    // multiply: thread (g = t&31, c0 = t>>5); attn4 in registers, 32 channels
    int g = t & 31;
    int c0 = t >> 5;
    float a0 = attn_s[g * 4 + 0];
    float a1 = attn_s[g * 4 + 1];
    float a2 = attn_s[g * 4 + 2];
    float a3 = attn_s[g * 4 + 3];
    size_t base = (size_t)img * CH * HW + (size_t)c0 * CCHUNK * HW
                + pix0 + g * 4;
    const float* xp = x + base;
    float* op = out + base;
#pragma unroll 8
    for (int i = 0; i < CCHUNK; ++i) {
        float4 v = *reinterpret_cast<const float4*>(xp + (size_t)i * HW);
        floatx4 o;
        o.x = v.x * a0; o.y = v.y * a1; o.z = v.z * a2; o.w = v.w * a3;
        __builtin_nontemporal_store(o, reinterpret_cast<floatx4*>(op + (size_t)i * HW));
    }
}

extern "C" void kernel_launch(void* const* d_in, const int* in_sizes, int n_in,
                              void* d_out, int out_size, void* d_ws, size_t ws_size,
                              hipStream_t stream) {
    const float* x    = (const float*)d_in[0];
    const float* wgt  = (const float*)d_in[1];
    const float* bias = (const float*)d_in[2];
    float* out = (float*)d_out;

    float4* pooled4 = (float4*)d_ws;     // NPIX floats = 512 KiB

    sa_pool<<<dim3(NBLK), dim3(256), 0, stream>>>(x, pooled4);
    sa_conv_mul<<<dim3(NBLK), dim3(256), 0, stream>>>(x, pooled4, wgt, bias, out);
}

// Round 6
// 74.597 us; speedup vs baseline: 1.1109x; 1.0776x over previous
//
#include <hip/hip_runtime.h>
#include <math.h>

#define BATCH 32
#define CH    256
#define HH    64
#define WW    64
#define HW    (HH * WW)                  // 4096
#define NPIX  (BATCH * HW)               // 131072
#define NTOT  ((size_t)BATCH * CH * HW)  // 33554432

// K1 geometry: 128 contiguous pixels (2 rows) x all 256 channels per block.
#define PIX_PER_BLK 128
#define GRP_PER_BLK 32                   // float4 pixel-groups
#define NCHUNK 8
#define CCHUNK 32
#define NBLK  (NPIX / PIX_PER_BLK)       // 1024

// K1: channel-wise mean+max -> pooled, in-block LDS combine, float4 loads.
// 1024 blocks x 256 threads (4 blocks/CU). Thread (g=t&31, c=t>>5).
__global__ __launch_bounds__(256) void sa_pool(
    const float* __restrict__ x, float4* __restrict__ pooled4) {
    __shared__ float4 sS[NCHUNK][GRP_PER_BLK];
    __shared__ float4 sM[NCHUNK][GRP_PER_BLK];
    int t = threadIdx.x;
    int g = t & 31;
    int c = t >> 5;
    int img = blockIdx.x >> 5;           // 32 blocks per image
    int seg = blockIdx.x & 31;
    int pix0 = seg * PIX_PER_BLK;
    const float* p = x + (size_t)img * CH * HW + (size_t)c * CCHUNK * HW
                   + pix0 + g * 4;
    float4 s = make_float4(0.f, 0.f, 0.f, 0.f);
    float4 m = make_float4(-INFINITY, -INFINITY, -INFINITY, -INFINITY);
#pragma unroll 8
    for (int i = 0; i < CCHUNK; ++i) {
        float4 v = *reinterpret_cast<const float4*>(p + (size_t)i * HW);
        s.x += v.x; s.y += v.y; s.z += v.z; s.w += v.w;
        m.x = fmaxf(m.x, v.x); m.y = fmaxf(m.y, v.y);
        m.z = fmaxf(m.z, v.z); m.w = fmaxf(m.w, v.w);
    }
    sS[c][g] = s;
    sM[c][g] = m;
    __syncthreads();
    if (t < GRP_PER_BLK) {
        float4 as = sS[0][t];
        float4 am = sM[0][t];
#pragma unroll
        for (int cc = 1; cc < NCHUNK; ++cc) {
            float4 bs = sS[cc][t];
            float4 bm = sM[cc][t];
            as.x += bs.x; as.y += bs.y; as.z += bs.z; as.w += bs.w;
            am.x = fmaxf(am.x, bm.x); am.y = fmaxf(am.y, bm.y);
            am.z = fmaxf(am.z, bm.z); am.w = fmaxf(am.w, bm.w);
        }
        const float inv = 1.0f / (float)CH;
        float4 o;
        o.x = as.x * inv + am.x; o.y = as.y * inv + am.y;
        o.z = as.z * inv + am.z; o.w = as.w * inv + am.w;
        pooled4[(img * HW + pix0) / 4 + t] = o;
    }
}

// K2: 7x7 SAME conv + bias + sigmoid -> attn. 512 blocks x 256.
__global__ __launch_bounds__(256) void sa_conv(
    const float* __restrict__ pooled, const float* __restrict__ wgt,
    const float* __restrict__ bias, float* __restrict__ attn) {
    int idx = blockIdx.x * blockDim.x + threadIdx.x;
    if (idx >= NPIX) return;
    int b  = idx >> 12;
    int hw = idx & 4095;
    int h  = hw >> 6;
    int w  = hw & 63;
    const float* pb = pooled + b * HW;
    float acc = bias[0];
#pragma unroll
    for (int kh = 0; kh < 7; ++kh) {
        int hh2 = h + kh - 3;
        if (hh2 < 0 || hh2 >= HH) continue;
#pragma unroll
        for (int kw = 0; kw < 7; ++kw) {
            int ww2 = w + kw - 3;
            if (ww2 < 0 || ww2 >= WW) continue;
            acc += pb[hh2 * WW + ww2] * wgt[kh * 7 + kw];
        }
    }
    attn[idx] = 1.0f / (1.0f + __expf(-acc));
}

// K3: out = x * attn, 1 float4 per thread, plain stores (round-1 best).
__global__ __launch_bounds__(256) void sa_mul(
    const float* __restrict__ x, const float* __restrict__ attn,
    float* __restrict__ out) {
    size_t i = ((size_t)blockIdx.x * blockDim.x + threadIdx.x) * 4;
    if (i >= NTOT) return;
    size_t bc = i >> 12;         // b*CH + c
    int hw    = (int)(i & 4095);
    int b     = (int)(bc >> 8);
    float4 xv = *reinterpret_cast<const float4*>(x + i);
    float4 av = *reinterpret_cast<const float4*>(attn + (size_t)b * HW + hw);
    float4 o;
    o.x = xv.x * av.x;
    o.y = xv.y * av.y;
    o.z = xv.z * av.z;
    o.w = xv.w * av.w;
    *reinterpret_cast<float4*>(out + i) = o;
}

extern "C" void kernel_launch(void* const* d_in, const int* in_sizes, int n_in,
                              void* d_out, int out_size, void* d_ws, size_t ws_size,
                              hipStream_t stream) {
    const float* x    = (const float*)d_in[0];
    const float* wgt  = (const float*)d_in[1];
    const float* bias = (const float*)d_in[2];
    float* out = (float*)d_out;

    // ws layout (floats): pooled [NPIX], attn [NPIX]
    float* pooled = (float*)d_ws;
    float* attn   = pooled + NPIX;

    sa_pool<<<dim3(NBLK), dim3(256), 0, stream>>>(
        x, reinterpret_cast<float4*>(pooled));
    sa_conv<<<dim3((NPIX + 255) / 256), dim3(256), 0, stream>>>(
        pooled, wgt, bias, attn);
    sa_mul<<<dim3((unsigned)((NTOT / 4 + 255) / 256)), dim3(256), 0, stream>>>(
        x, attn, out);
}